// Round 1
// baseline (1793.408 us; speedup 1.0000x reference)
//
#include <hip/hip_runtime.h>
#include <math.h>

#define FL 1025

typedef __bf16 bf16x8 __attribute__((ext_vector_type(8)));
typedef float  f32x4  __attribute__((ext_vector_type(4)));

static __device__ __forceinline__ bf16x8 ldfrag(const __bf16* p) {
  union { uint4 q; bf16x8 v; } u;
  u.q = *(const uint4*)p;
  return u.v;
}
static __device__ __forceinline__ float fexp(float x) { return __expf(x); }

// ---------------------------------------------------------------------------
// In-LDS radix-2 DIT FFT, 2048 points, 256 threads (verified rounds 1-3).
static __device__ __forceinline__ void fft2048_stages(float* re, float* im, int tid, int dir) {
  for (int len = 2; len <= 2048; len <<= 1) {
    int half = len >> 1;
    __syncthreads();
    for (int t = tid; t < 1024; t += 256) {
      int j  = t & (half - 1);
      int i0 = ((t & ~(half - 1)) << 1) | j;
      int i1 = i0 + half;
      float ang = (2.0f * (float)j) / (float)len;
      float wr = cospif(ang);
      float s  = sinpif(ang);
      float wi = (dir > 0) ? s : -s;
      float vr = re[i1], vi = im[i1];
      float tr = vr * wr - vi * wi;
      float ti = vr * wi + vi * wr;
      float ur = re[i0], ui = im[i0];
      re[i0] = ur + tr; im[i0] = ui + ti;
      re[i1] = ur - tr; im[i1] = ui - ti;
    }
  }
  __syncthreads();
}

// Pair-packed rfft: channels (2c2, 2c2+1) via one complex FFT + Hermitian
// unpack. QF3[t*16+b][k=1024][f], row stride 1028 (16B-aligned rows).
__global__ __launch_bounds__(256) void rfft3_kernel(const float* __restrict__ xT,
                                                    float* __restrict__ QF3) {
  __shared__ float re[2048];
  __shared__ float im[2048];
  int c2 = blockIdx.x, b = blockIdx.y, t = blockIdx.z, tid = threadIdx.x;
  const float* pa = xT + (((long long)t * 16 + b) * 512 + 2 * c2) * 2048;
  const float* pb = pa + 2048;
  float4 a0 = *(const float4*)(pa + tid * 8);
  float4 a1 = *(const float4*)(pa + tid * 8 + 4);
  float4 b0 = *(const float4*)(pb + tid * 8);
  float4 b1 = *(const float4*)(pb + tid * 8 + 4);
  float va[8] = {a0.x, a0.y, a0.z, a0.w, a1.x, a1.y, a1.z, a1.w};
  float vb[8] = {b0.x, b0.y, b0.z, b0.w, b1.x, b1.y, b1.z, b1.w};
#pragma unroll
  for (int j = 0; j < 8; j++) {
    int l = tid * 8 + j;
    int r = __brev((unsigned)l) >> 21;
    re[r] = va[j];
    im[r] = vb[j];
  }
  fft2048_stages(re, im, tid, -1);
  float* base = QF3 + ((long long)t * 16 + b) * 1052672;
  for (int f = tid; f <= 1024; f += 256) {
    int g = (2048 - f) & 2047;
    float fr = re[f], fi = im[f], gr = re[g], gi = im[g];
    float Xar = 0.5f * (fr + gr), Xai = 0.5f * (fi - gi);
    float Xbr = 0.5f * (fi + gi), Xbi = 0.5f * (gr - fr);
    base[(long long)(2 * c2) * 1028 + f]       = Xar;
    base[(long long)(512 + 2 * c2) * 1028 + f] = Xai;
    base[(long long)(2 * c2 + 1) * 1028 + f]   = Xbr;
    base[(long long)(513 + 2 * c2) * 1028 + f] = Xbi;
  }
}

// Pair-packed irfft: output channels (2d2, 2d2+1) from ybT rows 4d2..4d2+3.
// Zeroes Im at DC/Nyquist (c2r semantics). float2 stores to out.
__global__ __launch_bounds__(256) void irfft3_kernel(const float* __restrict__ ybT,
                                                     float* __restrict__ out) {
  __shared__ float Yar[FL], Yai[FL], Ybr[FL], Ybi[FL];
  __shared__ float re[2048];
  __shared__ float im[2048];
  int d2 = blockIdx.x, b = blockIdx.y, tid = threadIdx.x;
  const float* yp = ybT + ((long long)b * 1024 + 4 * d2) * 1025;
  for (int f = tid; f <= 1024; f += 256) {
    Yar[f] = yp[f];
    Yai[f] = yp[1025 + f];
    Ybr[f] = yp[2050 + f];
    Ybi[f] = yp[3075 + f];
  }
  __syncthreads();
  if (tid == 0) { Yai[0] = 0.f; Yai[1024] = 0.f; Ybi[0] = 0.f; Ybi[1024] = 0.f; }
  __syncthreads();
  for (int i = tid; i < 2048; i += 256) {
    int j = __brev((unsigned)i) >> 21;
    float rr, ii;
    if (j <= 1024) { rr = Yar[j] - Ybi[j]; ii = Yai[j] + Ybr[j]; }
    else { int f = 2048 - j; rr = Yar[f] + Ybi[f]; ii = Ybr[f] - Yai[f]; }
    re[i] = rr; im[i] = ii;
  }
  fft2048_stages(re, im, tid, +1);
  float* op = out + (long long)b * 2048 * 512 + 2 * d2;
  const float sc = 1.0f / 2048.0f;
  for (int l = tid; l < 2048; l += 256) {
    float2 v = {re[l] * sc, im[l] * sc};
    *(float2*)(op + (long long)l * 512) = v;
  }
}

// ---------------------------------------------------------------------------
// x (b, 2048, 512) -> xT (b, 512, 2048), 3 inputs in one launch.
__global__ __launch_bounds__(256) void transpose_x(const float* __restrict__ q,
                                                   const float* __restrict__ k,
                                                   const float* __restrict__ v,
                                                   float* __restrict__ xT) {
  __shared__ float t[32][33];
  int z = blockIdx.z;
  int ti = z >> 4, b = z & 15;
  const float* x = (ti == 0) ? q : (ti == 1) ? k : v;
  int l0 = blockIdx.x * 32, c0 = blockIdx.y * 32;
  int tx = threadIdx.x & 31, ty = threadIdx.x >> 5;
  for (int i = ty; i < 32; i += 8)
    t[i][tx] = x[((long long)b * 2048 + l0 + i) * 512 + c0 + tx];
  __syncthreads();
  float* dst = xT + ((long long)ti * 16 + b) * 512 * 2048;
  for (int i = ty; i < 32; i += 8)
    dst[((long long)(c0 + i)) * 2048 + l0 + tx] = t[tx][i];
}

// ---------------------------------------------------------------------------
// One-shot setup: pack_w (split bf16), pack_wo, wf column sums, bias gather.
__global__ __launch_bounds__(256) void setup_pack(
    const float* __restrict__ Wq, const float* __restrict__ Wk,
    const float* __restrict__ Wv, const float* __restrict__ Wo,
    const float* __restrict__ bq, const float* __restrict__ bk,
    const float* __restrict__ bv,
    __bf16* __restrict__ Wth, __bf16* __restrict__ Wtl,
    __bf16* __restrict__ Woh, float* __restrict__ wf3, float* __restrict__ bias3) {
  int bx = blockIdx.x, tid = threadIdx.x;
  if (bx < 6144) {
    int e = bx * 256 + tid;               // 0 .. 1,572,863
    int t = e >> 19, local = e & 524287;
    const float* W = (t == 0) ? Wq : (t == 1) ? Wk : Wv;
    int o = local >> 10, kk = local & 1023;
    int c = kk & 511, j = kk >> 9;
    float v = W[(long long)o * 1536 + c * 3 + j];
    __bf16 h = (__bf16)v;
    Wth[e] = h;
    Wtl[e] = (__bf16)(v - (float)h);
  } else if (bx < 8192) {
    int e = (bx - 6144) * 256 + tid;      // 0 .. 524,287
    Woh[e] = (__bf16)Wo[e];
  } else if (bx < 8198) {
    int idx = (bx - 8192) * 256 + tid;    // 0 .. 1535
    int t = idx / 512, o = idx & 511;
    const float* W = (t == 0) ? Wq : (t == 1) ? Wk : Wv;
    float s = 0.f;
    for (int c = 0; c < 512; c++) s += W[(long long)o * 1536 + c * 3 + 2];
    wf3[idx] = s;
  } else {
    int idx = (bx - 8198) * 256 + tid;    // 0 .. 1535
    int t = idx / 512, o = idx & 511;
    bias3[idx] = (t == 0) ? bq[o] : (t == 1) ? bk[o] : bv[o];
  }
}

// ---------------------------------------------------------------------------
// Fused projection GEMM: A = QF3 (fp32, [k][f] layout, transposed+split in
// staging), B = Wt hi/lo planes. z = t*16+b. 3-term split compute.
// t<2 -> split bf16 qh/kh; t==2 -> vhT layout directly.
__global__ __launch_bounds__(256) void proj_gemm(
    const float* __restrict__ QF3,
    const __bf16* __restrict__ Wth, const __bf16* __restrict__ Wtl,
    const float* __restrict__ wf3, const float* __restrict__ bias3,
    __bf16* __restrict__ qhh, __bf16* __restrict__ qhl,
    __bf16* __restrict__ khh, __bf16* __restrict__ khl,
    __bf16* __restrict__ vhT, float uscale) {
  __shared__ __bf16 As[2][128][40];
  __shared__ __bf16 Bs[2][128][40];
  int tid = threadIdx.x;
  int wid = tid >> 6, lane = tid & 63;
  int lrow = lane & 15, quad = lane >> 4;
  int m0 = blockIdx.x * 128, n0 = blockIdx.y * 128;
  int z = blockIdx.z;
  int t = z >> 4, b = z & 15;
  const float* Ab = QF3 + (long long)z * 1052672;
  const __bf16* Bbh = Wth + (long long)t * 524288;
  const __bf16* Bbl = Wtl + (long long)t * 524288;

  int wm0 = (wid & 1) * 64, wn0 = (wid >> 1) * 64;
  // A staging: transpose fp32 [k][f] -> LDS [f][k] with on-the-fly split
  int floc = tid & 127;
  int kg = (tid >> 7) * 4;                 // 0 or 4
  const float* Acol = Ab + min(m0 + floc, 1024);
  // B staging: plain copy of pre-split planes
  int srow = tid >> 1, shalf = tid & 1;

  f32x4 acc[4][4];
#pragma unroll
  for (int i = 0; i < 4; i++)
#pragma unroll
    for (int j = 0; j < 4; j++) acc[i][j] = (f32x4){0.f, 0.f, 0.f, 0.f};

  for (int k0 = 0; k0 < 1024; k0 += 32) {
#pragma unroll
    for (int it = 0; it < 4; it++) {
      int kko = kg + it * 8;               // 0,8,16,24 (+4)
      float v0 = Acol[(long long)(k0 + kko + 0) * 1028];
      float v1 = Acol[(long long)(k0 + kko + 1) * 1028];
      float v2 = Acol[(long long)(k0 + kko + 2) * 1028];
      float v3 = Acol[(long long)(k0 + kko + 3) * 1028];
      __bf16 h0 = (__bf16)v0, h1 = (__bf16)v1, h2 = (__bf16)v2, h3 = (__bf16)v3;
      unsigned short u0, u1, u2, u3;
      __builtin_memcpy(&u0, &h0, 2); __builtin_memcpy(&u1, &h1, 2);
      __builtin_memcpy(&u2, &h2, 2); __builtin_memcpy(&u3, &h3, 2);
      uint2 hu = make_uint2((unsigned)u0 | ((unsigned)u1 << 16),
                            (unsigned)u2 | ((unsigned)u3 << 16));
      __bf16 l0 = (__bf16)(v0 - (float)h0), l1 = (__bf16)(v1 - (float)h1);
      __bf16 l2 = (__bf16)(v2 - (float)h2), l3 = (__bf16)(v3 - (float)h3);
      __builtin_memcpy(&u0, &l0, 2); __builtin_memcpy(&u1, &l1, 2);
      __builtin_memcpy(&u2, &l2, 2); __builtin_memcpy(&u3, &l3, 2);
      uint2 lu = make_uint2((unsigned)u0 | ((unsigned)u1 << 16),
                            (unsigned)u2 | ((unsigned)u3 << 16));
      *(uint2*)&As[0][floc][kko] = hu;
      *(uint2*)&As[1][floc][kko] = lu;
    }
    {
      const __bf16* s = Bbh + (long long)(n0 + srow) * 1024 + k0 + shalf * 16;
      uint4* d = (uint4*)&Bs[0][srow][shalf * 16];
      d[0] = ((const uint4*)s)[0]; d[1] = ((const uint4*)s)[1];
      s = Bbl + (long long)(n0 + srow) * 1024 + k0 + shalf * 16;
      d = (uint4*)&Bs[1][srow][shalf * 16];
      d[0] = ((const uint4*)s)[0]; d[1] = ((const uint4*)s)[1];
    }
    __syncthreads();

    bf16x8 bh[4], bl[4];
#pragma unroll
    for (int nt = 0; nt < 4; nt++) {
      int r = wn0 + nt * 16 + lrow;
      bh[nt] = ldfrag(&Bs[0][r][quad * 8]);
      bl[nt] = ldfrag(&Bs[1][r][quad * 8]);
    }
#pragma unroll
    for (int mt = 0; mt < 4; mt++) {
      int r = wm0 + mt * 16 + lrow;
      bf16x8 ah = ldfrag(&As[0][r][quad * 8]);
      bf16x8 al = ldfrag(&As[1][r][quad * 8]);
#pragma unroll
      for (int nt = 0; nt < 4; nt++) {
        acc[mt][nt] = __builtin_amdgcn_mfma_f32_16x16x32_bf16(ah, bh[nt], acc[mt][nt], 0, 0, 0);
        acc[mt][nt] = __builtin_amdgcn_mfma_f32_16x16x32_bf16(ah, bl[nt], acc[mt][nt], 0, 0, 0);
        acc[mt][nt] = __builtin_amdgcn_mfma_f32_16x16x32_bf16(al, bh[nt], acc[mt][nt], 0, 0, 0);
      }
    }
    __syncthreads();
  }

  // epilogue
  __bf16* Ch = (t == 0) ? qhh : khh;
  __bf16* Cl = (t == 0) ? qhl : khl;
#pragma unroll
  for (int mt = 0; mt < 4; mt++) {
#pragma unroll
    for (int nt = 0; nt < 4; nt++) {
      int gn = n0 + wn0 + nt * 16 + lrow;
      float bn = bias3[t * 512 + gn];
      float vn = wf3[t * 512 + gn];
      int gmb = m0 + wm0 + mt * 16 + quad * 4;
      if (t < 2) {
#pragma unroll
        for (int r = 0; r < 4; r++) {
          int gm = gmb + r;
          if (gm < FL) {
            float val = acc[mt][nt][r] + bn + uscale * (float)gm * vn;
            long long o = ((long long)b * FL + gm) * 512 + gn;
            __bf16 h = (__bf16)val;
            Ch[o] = h;
            Cl[o] = (__bf16)(val - (float)h);
          }
        }
      } else {
        int hh = gn >> 6, dd = gn & 63;
        long long ob = ((long long)(b * 8 + hh) * 64 + dd) * 1152;
#pragma unroll
        for (int r = 0; r < 4; r++) {
          int gm = gmb + r;
          if (gm < FL) {
            float val = acc[mt][nt][r] + bn + uscale * (float)gm * vn;
            vhT[ob + gm] = (__bf16)val;
          }
        }
      }
    }
  }
}

// ---------------------------------------------------------------------------
// Out projection GEMM (1-term): A = ctx bf16 [b][f][512], B = Woh [o][512].
// Writes ybT[b][o=1024][f=1025] fp32 (transposed for coalesced irfft reads).
__global__ __launch_bounds__(256) void oproj_gemm(
    const __bf16* __restrict__ ctx, const __bf16* __restrict__ Woh,
    const float* __restrict__ bo, float* __restrict__ ybT) {
  __shared__ __bf16 As[128][40];
  __shared__ __bf16 Bs[128][40];
  int tid = threadIdx.x;
  int wid = tid >> 6, lane = tid & 63;
  int lrow = lane & 15, quad = lane >> 4;
  int m0 = blockIdx.x * 128, n0 = blockIdx.y * 128;
  int z = blockIdx.z;   // b
  const __bf16* Ab = ctx + (long long)z * 524800;
  int wm0 = (wid & 1) * 64, wn0 = (wid >> 1) * 64;
  int srow = tid >> 1, shalf = tid & 1;
  int arow = min(m0 + srow, FL - 1);

  f32x4 acc[4][4];
#pragma unroll
  for (int i = 0; i < 4; i++)
#pragma unroll
    for (int j = 0; j < 4; j++) acc[i][j] = (f32x4){0.f, 0.f, 0.f, 0.f};

  for (int k0 = 0; k0 < 512; k0 += 32) {
    {
      const __bf16* s = Ab + (long long)arow * 512 + k0 + shalf * 16;
      uint4* d = (uint4*)&As[srow][shalf * 16];
      d[0] = ((const uint4*)s)[0]; d[1] = ((const uint4*)s)[1];
      s = Woh + (long long)(n0 + srow) * 512 + k0 + shalf * 16;
      d = (uint4*)&Bs[srow][shalf * 16];
      d[0] = ((const uint4*)s)[0]; d[1] = ((const uint4*)s)[1];
    }
    __syncthreads();
    bf16x8 bh[4];
#pragma unroll
    for (int nt = 0; nt < 4; nt++) bh[nt] = ldfrag(&Bs[wn0 + nt * 16 + lrow][quad * 8]);
#pragma unroll
    for (int mt = 0; mt < 4; mt++) {
      bf16x8 ah = ldfrag(&As[wm0 + mt * 16 + lrow][quad * 8]);
#pragma unroll
      for (int nt = 0; nt < 4; nt++)
        acc[mt][nt] = __builtin_amdgcn_mfma_f32_16x16x32_bf16(ah, bh[nt], acc[mt][nt], 0, 0, 0);
    }
    __syncthreads();
  }

#pragma unroll
  for (int mt = 0; mt < 4; mt++) {
#pragma unroll
    for (int nt = 0; nt < 4; nt++) {
      int gn = n0 + wn0 + nt * 16 + lrow;
      float bn = bo[gn];
      int gmb = m0 + wm0 + mt * 16 + quad * 4;
      long long ob = (long long)z * 1049600 + (long long)gn * 1025;
#pragma unroll
      for (int r = 0; r < 4; r++) {
        int gm = gmb + r;
        if (gm < FL) ybT[ob + gm] = acc[mt][nt][r] + bn;
      }
    }
  }
}

// ---------------------------------------------------------------------------
// Fused flash attention (verified round 3): per (b,h), 128-row Q tile,
// two-pass exact online softmax; writes normalized attn (fp32) + ctx (bf16).
static __device__ __forceinline__ void compute_S_tile(
    const __bf16 (*Kh)[72], const __bf16 (*Kl)[72],
    const bf16x8 (&qf)[2][2], int lrow, int quad, int n0, f32x4* sa) {
#pragma unroll
  for (int nt = 0; nt < 8; nt++) sa[nt] = (f32x4){0.f, 0.f, 0.f, 0.f};
#pragma unroll
  for (int kit = 0; kit < 2; kit++) {
#pragma unroll
    for (int nt = 0; nt < 8; nt++) {
      bf16x8 kh = ldfrag(&Kh[nt * 16 + lrow][kit * 32 + quad * 8]);
      bf16x8 kl = ldfrag(&Kl[nt * 16 + lrow][kit * 32 + quad * 8]);
      sa[nt] = __builtin_amdgcn_mfma_f32_16x16x32_bf16(qf[0][kit], kh, sa[nt], 0, 0, 0);
      sa[nt] = __builtin_amdgcn_mfma_f32_16x16x32_bf16(qf[0][kit], kl, sa[nt], 0, 0, 0);
      sa[nt] = __builtin_amdgcn_mfma_f32_16x16x32_bf16(qf[1][kit], kh, sa[nt], 0, 0, 0);
    }
  }
#pragma unroll
  for (int nt = 0; nt < 8; nt++) {
    int gn = n0 + nt * 16 + lrow;
    bool ok = gn < FL;
#pragma unroll
    for (int r = 0; r < 4; r++) sa[nt][r] = ok ? sa[nt][r] * 0.125f : -INFINITY;
  }
}

__global__ __launch_bounds__(512) void flash_kernel(
    const __bf16* __restrict__ qh_h, const __bf16* __restrict__ qh_l,
    const __bf16* __restrict__ kh_h, const __bf16* __restrict__ kh_l,
    const __bf16* __restrict__ vhT,
    float* __restrict__ attn, __bf16* __restrict__ ctxb) {
  __shared__ __align__(16) char smem[54272];
  __bf16 (*Kh)[72]  = (__bf16 (*)[72])smem;
  __bf16 (*Kl)[72]  = (__bf16 (*)[72])(smem + 18432);
  __bf16 (*P)[136]  = (__bf16 (*)[136])smem;          // aliases Kh/Kl
  __bf16 (*Bv)[136] = (__bf16 (*)[136])(smem + 36864);

  int tid = threadIdx.x;
  int wid = tid >> 6, lane = tid & 63;
  int lrow = lane & 15, quad = lane >> 4;
  int f0 = blockIdx.x * 128;
  int z = blockIdx.z;
  int b = z >> 3, h = z & 7;

  bf16x8 qf[2][2];
  {
    int rowq = min(f0 + wid * 16 + lrow, FL - 1);
    long long base = ((long long)b * FL + rowq) * 512 + h * 64 + quad * 8;
#pragma unroll
    for (int kit = 0; kit < 2; kit++) {
      qf[0][kit] = ldfrag(qh_h + base + kit * 32);
      qf[1][kit] = ldfrag(qh_l + base + kit * 32);
    }
  }

  int sp = tid >> 8, srw = (tid >> 1) & 127, shalf = tid & 1;
  const __bf16* ksrc0 = (sp ? kh_l : kh_h) + (long long)b * FL * 512 + h * 64 + shalf * 32;
  __bf16* kdst = (sp ? Kl[srw] : Kh[srw]) + shalf * 32;

  float m_i[4], l_i[4];
#pragma unroll
  for (int r = 0; r < 4; r++) { m_i[r] = -INFINITY; l_i[r] = 0.f; }

  f32x4 sa[8];

  // ---- pass 1: exact online (m, l) ----
  for (int nt0 = 0; nt0 < 9; nt0++) {
    __syncthreads();
    {
      int srowg = min(nt0 * 128 + srw, FL - 1);
      const __bf16* s = ksrc0 + (long long)srowg * 512;
#pragma unroll
      for (int u = 0; u < 4; u++) ((uint4*)kdst)[u] = ((const uint4*)s)[u];
    }
    __syncthreads();
    compute_S_tile(Kh, Kl, qf, lrow, quad, nt0 * 128, sa);
#pragma unroll
    for (int r = 0; r < 4; r++) {
      float mx = -INFINITY;
#pragma unroll
      for (int nt = 0; nt < 8; nt++) mx = fmaxf(mx, sa[nt][r]);
      for (int o = 1; o < 16; o <<= 1) mx = fmaxf(mx, __shfl_xor(mx, o, 64));
      float mn = fmaxf(m_i[r], mx);
      float al = fexp(m_i[r] - mn);
      float ps = 0.f;
#pragma unroll
      for (int nt = 0; nt < 8; nt++) ps += fexp(sa[nt][r] - mn);
      for (int o = 1; o < 16; o <<= 1) ps += __shfl_xor(ps, o, 64);
      l_i[r] = l_i[r] * al + ps;
      m_i[r] = mn;
    }
  }

  float rl[4];
#pragma unroll
  for (int r = 0; r < 4; r++) rl[r] = 1.0f / l_i[r];

  f32x4 oa[4];
#pragma unroll
  for (int j = 0; j < 4; j++) oa[j] = (f32x4){0.f, 0.f, 0.f, 0.f};

  int vrow = tid >> 3, voff = (tid & 7) * 16;
  const __bf16* vsrc0 = vhT + ((long long)z * 64 + vrow) * 1152 + voff;
  __bf16* vdst = &Bv[vrow][voff];

  // ---- pass 2: recompute S, emit attn, accumulate O = P*V ----
  float* attnz = attn + (long long)z * 1050625;
  for (int nt0 = 0; nt0 < 9; nt0++) {
    __syncthreads();
    {
      int srowg = min(nt0 * 128 + srw, FL - 1);
      const __bf16* s = ksrc0 + (long long)srowg * 512;
#pragma unroll
      for (int u = 0; u < 4; u++) ((uint4*)kdst)[u] = ((const uint4*)s)[u];
      const __bf16* vs = vsrc0 + nt0 * 128;
      ((uint4*)vdst)[0] = ((const uint4*)vs)[0];
      ((uint4*)vdst)[1] = ((const uint4*)vs)[1];
    }
    __syncthreads();
    compute_S_tile(Kh, Kl, qf, lrow, quad, nt0 * 128, sa);
    __syncthreads();
#pragma unroll
    for (int nt = 0; nt < 8; nt++) {
      int gn = nt0 * 128 + nt * 16 + lrow;
#pragma unroll
      for (int r = 0; r < 4; r++) {
        float p = fexp(sa[nt][r] - m_i[r]) * rl[r];
        int lm = wid * 16 + quad * 4 + r;
        int gm = f0 + lm;
        if (gm < FL && gn < FL) attnz[(long long)gm * FL + gn] = p;
        P[lm][nt * 16 + lrow] = (__bf16)p;
      }
    }
#pragma unroll
    for (int kk = 0; kk < 4; kk++) {
      bf16x8 pf = ldfrag(&P[wid * 16 + lrow][kk * 32 + quad * 8]);
#pragma unroll
      for (int nto = 0; nto < 4; nto++) {
        bf16x8 vf = ldfrag(&Bv[nto * 16 + lrow][kk * 32 + quad * 8]);
        oa[nto] = __builtin_amdgcn_mfma_f32_16x16x32_bf16(pf, vf, oa[nto], 0, 0, 0);
      }
    }
  }

#pragma unroll
  for (int nto = 0; nto < 4; nto++) {
#pragma unroll
    for (int r = 0; r < 4; r++) {
      int gm = f0 + wid * 16 + quad * 4 + r;
      if (gm < FL)
        ctxb[((long long)b * FL + gm) * 512 + h * 64 + nto * 16 + lrow] = (__bf16)oa[nto][r];
    }
  }
}

// ---------------------------------------------------------------------------
extern "C" void kernel_launch(void* const* d_in, const int* in_sizes, int n_in,
                              void* d_out, int out_size, void* d_ws, size_t ws_size,
                              hipStream_t stream) {
  (void)in_sizes; (void)n_in; (void)out_size; (void)ws_size;
  const float* q  = (const float*)d_in[0];
  const float* k  = (const float*)d_in[1];
  const float* v  = (const float*)d_in[2];
  const float* Wq = (const float*)d_in[3];
  const float* bq = (const float*)d_in[4];
  const float* Wk = (const float*)d_in[5];
  const float* bk = (const float*)d_in[6];
  const float* Wv = (const float*)d_in[7];
  const float* bv = (const float*)d_in[8];
  const float* Wo = (const float*)d_in[9];
  const float* bo = (const float*)d_in[10];

  float* outp = (float*)d_out;
  float* attn = outp + (long long)16 * 2048 * 512;

  float* ws = (float*)d_ws;
  float*  xT   = ws;                                   // 50,331,648 fl
  float*  QF3  = xT + 50331648;                        // 50,528,256 fl (48 x 1024 x 1028)
  float*  wf3  = QF3 + 50528256;                       //      1,536 fl
  float*  bias3= wf3 + 1536;                           //      1,536 fl
  __bf16* Wth  = (__bf16*)(bias3 + 1536);              //  1,572,864
  __bf16* Wtl  = Wth + 1572864;
  __bf16* Woh  = Wtl + 1572864;                        //    524,288
  __bf16* qhh  = Woh + 524288;                         //  8,396,800 each
  __bf16* qhl  = qhh + 8396800;
  __bf16* khh  = qhl + 8396800;
  __bf16* khl  = khh + 8396800;
  __bf16* vhT  = khl + 8396800;                        //  9,437,184
  __bf16* ctx  = (__bf16*)QF3;                         // alias (QF3 dead post-proj)
  float*  ybT  = xT;                                   // alias (xT dead post-rfft)

  transpose_x<<<dim3(64, 16, 48), 256, 0, stream>>>(q, k, v, xT);
  setup_pack<<<dim3(8204, 1, 1), 256, 0, stream>>>(Wq, Wk, Wv, Wo, bq, bk, bv,
                                                   Wth, Wtl, Woh, wf3, bias3);
  rfft3_kernel<<<dim3(256, 16, 3), 256, 0, stream>>>(xT, QF3);

  proj_gemm<<<dim3(9, 4, 48), 256, 0, stream>>>(
      QF3, Wth, Wtl, wf3, bias3, qhh, qhl, khh, khl, vhT, 1.0f / 2048.0f);

  flash_kernel<<<dim3(9, 1, 128), 512, 0, stream>>>(
      qhh, qhl, khh, khl, vhT, attn, ctx);

  oproj_gemm<<<dim3(9, 8, 16), 256, 0, stream>>>(ctx, Woh, bo, ybT);

  irfft3_kernel<<<dim3(256, 16), 256, 0, stream>>>(ybT, outp);
}

// Round 3
// 1679.535 us; speedup vs baseline: 1.0678x; 1.0678x over previous
//
#include <hip/hip_runtime.h>
#include <math.h>

#define FL 1025

typedef __bf16 bf16x8 __attribute__((ext_vector_type(8)));
typedef float  f32x4  __attribute__((ext_vector_type(4)));

static __device__ __forceinline__ bf16x8 ldfrag(const __bf16* p) {
  union { uint4 q; bf16x8 v; } u;
  u.q = *(const uint4*)p;
  return u.v;
}
static __device__ __forceinline__ float fexp(float x) { return __expf(x); }

// Pack split-bf16 (hi, lo) of a float into one uint32: hi in low 16 bits.
static __device__ __forceinline__ unsigned pack_hl(float v) {
  __bf16 h = (__bf16)v;
  float hf = (float)h;
  __bf16 l = (__bf16)(v - hf);
  unsigned short uh, ul;
  __builtin_memcpy(&uh, &h, 2);
  __builtin_memcpy(&ul, &l, 2);
  return (unsigned)uh | ((unsigned)ul << 16);
}

// ---------------------------------------------------------------------------
// In-LDS radix-2 DIT FFT, 2048 points, 256 threads (verified rounds 1-3).
static __device__ __forceinline__ void fft2048_stages(float* re, float* im, int tid, int dir) {
  for (int len = 2; len <= 2048; len <<= 1) {
    int half = len >> 1;
    __syncthreads();
    for (int t = tid; t < 1024; t += 256) {
      int j  = t & (half - 1);
      int i0 = ((t & ~(half - 1)) << 1) | j;
      int i1 = i0 + half;
      float ang = (2.0f * (float)j) / (float)len;
      float wr = cospif(ang);
      float s  = sinpif(ang);
      float wi = (dir > 0) ? s : -s;
      float vr = re[i1], vi = im[i1];
      float tr = vr * wr - vi * wi;
      float ti = vr * wi + vi * wr;
      float ur = re[i0], ui = im[i0];
      re[i0] = ur + tr; im[i0] = ui + ti;
      re[i1] = ur - tr; im[i1] = ui - ti;
    }
  }
  __syncthreads();
}

// Pair-packed rfft: channels (2c2, 2c2+1) via one complex FFT + Hermitian
// unpack. QF3[t*16+b][k=1024][f], row stride 1028 (16B-aligned rows).
// Writes pre-split bf16 pair packed in uint32 (hi|lo<<16) per element.
__global__ __launch_bounds__(256) void rfft3_kernel(const float* __restrict__ xT,
                                                    unsigned* __restrict__ QF3) {
  __shared__ float re[2048];
  __shared__ float im[2048];
  int c2 = blockIdx.x, b = blockIdx.y, t = blockIdx.z, tid = threadIdx.x;
  const float* pa = xT + (((long long)t * 16 + b) * 512 + 2 * c2) * 2048;
  const float* pb = pa + 2048;
  float4 a0 = *(const float4*)(pa + tid * 8);
  float4 a1 = *(const float4*)(pa + tid * 8 + 4);
  float4 b0 = *(const float4*)(pb + tid * 8);
  float4 b1 = *(const float4*)(pb + tid * 8 + 4);
  float va[8] = {a0.x, a0.y, a0.z, a0.w, a1.x, a1.y, a1.z, a1.w};
  float vb[8] = {b0.x, b0.y, b0.z, b0.w, b1.x, b1.y, b1.z, b1.w};
#pragma unroll
  for (int j = 0; j < 8; j++) {
    int l = tid * 8 + j;
    int r = __brev((unsigned)l) >> 21;
    re[r] = va[j];
    im[r] = vb[j];
  }
  fft2048_stages(re, im, tid, -1);
  unsigned* base = QF3 + ((long long)t * 16 + b) * 1052672;
  for (int f = tid; f <= 1024; f += 256) {
    int g = (2048 - f) & 2047;
    float fr = re[f], fi = im[f], gr = re[g], gi = im[g];
    float Xar = 0.5f * (fr + gr), Xai = 0.5f * (fi - gi);
    float Xbr = 0.5f * (fi + gi), Xbi = 0.5f * (gr - fr);
    base[(long long)(2 * c2) * 1028 + f]       = pack_hl(Xar);
    base[(long long)(512 + 2 * c2) * 1028 + f] = pack_hl(Xai);
    base[(long long)(2 * c2 + 1) * 1028 + f]   = pack_hl(Xbr);
    base[(long long)(513 + 2 * c2) * 1028 + f] = pack_hl(Xbi);
  }
}

// Pair-packed irfft: output channels (2d2, 2d2+1) from ybT rows 4d2..4d2+3.
// Zeroes Im at DC/Nyquist (c2r semantics). float2 stores to out.
// XCD-aware swizzle (4096 blocks, 512/XCD, bijective).
__global__ __launch_bounds__(256) void irfft3_kernel(const float* __restrict__ ybT,
                                                     float* __restrict__ out) {
  __shared__ float Yar[FL], Yai[FL], Ybr[FL], Ybi[FL];
  __shared__ float re[2048];
  __shared__ float im[2048];
  int lin = blockIdx.y * 256 + blockIdx.x;
  int w = (lin & 7) * 512 + (lin >> 3);
  int d2 = w & 255;
  int b = w >> 8;
  int tid = threadIdx.x;
  const float* yp = ybT + ((long long)b * 1024 + 4 * d2) * 1025;
  for (int f = tid; f <= 1024; f += 256) {
    Yar[f] = yp[f];
    Yai[f] = yp[1025 + f];
    Ybr[f] = yp[2050 + f];
    Ybi[f] = yp[3075 + f];
  }
  __syncthreads();
  if (tid == 0) { Yai[0] = 0.f; Yai[1024] = 0.f; Ybi[0] = 0.f; Ybi[1024] = 0.f; }
  __syncthreads();
  for (int i = tid; i < 2048; i += 256) {
    int j = __brev((unsigned)i) >> 21;
    float rr, ii;
    if (j <= 1024) { rr = Yar[j] - Ybi[j]; ii = Yai[j] + Ybr[j]; }
    else { int f = 2048 - j; rr = Yar[f] + Ybi[f]; ii = Ybr[f] - Yai[f]; }
    re[i] = rr; im[i] = ii;
  }
  fft2048_stages(re, im, tid, +1);
  float* op = out + (long long)b * 2048 * 512 + 2 * d2;
  const float sc = 1.0f / 2048.0f;
  for (int l = tid; l < 2048; l += 256) {
    float2 v = {re[l] * sc, im[l] * sc};
    *(float2*)(op + (long long)l * 512) = v;
  }
}

// ---------------------------------------------------------------------------
// x (b, 2048, 512) -> xT (b, 512, 2048), 3 inputs in one launch.
__global__ __launch_bounds__(256) void transpose_x(const float* __restrict__ q,
                                                   const float* __restrict__ k,
                                                   const float* __restrict__ v,
                                                   float* __restrict__ xT) {
  __shared__ float t[32][33];
  int z = blockIdx.z;
  int ti = z >> 4, b = z & 15;
  const float* x = (ti == 0) ? q : (ti == 1) ? k : v;
  int l0 = blockIdx.x * 32, c0 = blockIdx.y * 32;
  int tx = threadIdx.x & 31, ty = threadIdx.x >> 5;
  for (int i = ty; i < 32; i += 8)
    t[i][tx] = x[((long long)b * 2048 + l0 + i) * 512 + c0 + tx];
  __syncthreads();
  float* dst = xT + ((long long)ti * 16 + b) * 512 * 2048;
  for (int i = ty; i < 32; i += 8)
    dst[((long long)(c0 + i)) * 2048 + l0 + tx] = t[tx][i];
}

// ---------------------------------------------------------------------------
// One-shot setup: pack_w (split bf16), pack_wo, wf column sums, bias gather.
__global__ __launch_bounds__(256) void setup_pack(
    const float* __restrict__ Wq, const float* __restrict__ Wk,
    const float* __restrict__ Wv, const float* __restrict__ Wo,
    const float* __restrict__ bq, const float* __restrict__ bk,
    const float* __restrict__ bv,
    __bf16* __restrict__ Wth, __bf16* __restrict__ Wtl,
    __bf16* __restrict__ Woh, float* __restrict__ wf3, float* __restrict__ bias3) {
  int bx = blockIdx.x, tid = threadIdx.x;
  if (bx < 6144) {
    int e = bx * 256 + tid;               // 0 .. 1,572,863
    int t = e >> 19, local = e & 524287;
    const float* W = (t == 0) ? Wq : (t == 1) ? Wk : Wv;
    int o = local >> 10, kk = local & 1023;
    int c = kk & 511, j = kk >> 9;
    float v = W[(long long)o * 1536 + c * 3 + j];
    __bf16 h = (__bf16)v;
    Wth[e] = h;
    Wtl[e] = (__bf16)(v - (float)h);
  } else if (bx < 8192) {
    int e = (bx - 6144) * 256 + tid;      // 0 .. 524,287
    Woh[e] = (__bf16)Wo[e];
  } else if (bx < 8198) {
    int idx = (bx - 8192) * 256 + tid;    // 0 .. 1535
    int t = idx / 512, o = idx & 511;
    const float* W = (t == 0) ? Wq : (t == 1) ? Wk : Wv;
    float s = 0.f;
    for (int c = 0; c < 512; c++) s += W[(long long)o * 1536 + c * 3 + 2];
    wf3[idx] = s;
  } else {
    int idx = (bx - 8198) * 256 + tid;    // 0 .. 1535
    int t = idx / 512, o = idx & 511;
    bias3[idx] = (t == 0) ? bq[o] : (t == 1) ? bk[o] : bv[o];
  }
}

// ---------------------------------------------------------------------------
// Fused projection GEMM: A = QF3 (packed split-bf16 uint32, [k][f] layout),
// B = Wt hi/lo planes. z = t*16+b. 3-term split compute.
// t<2 -> split bf16 qh/kh; t==2 -> vhT layout directly.
// A-staging is pure bit-unpack; XCD-aware swizzle (1728 blocks, 216/XCD).
__global__ __launch_bounds__(256) void proj_gemm(
    const unsigned* __restrict__ QF3,
    const __bf16* __restrict__ Wth, const __bf16* __restrict__ Wtl,
    const float* __restrict__ wf3, const float* __restrict__ bias3,
    __bf16* __restrict__ qhh, __bf16* __restrict__ qhl,
    __bf16* __restrict__ khh, __bf16* __restrict__ khl,
    __bf16* __restrict__ vhT, float uscale) {
  __shared__ __bf16 As[2][128][40];
  __shared__ __bf16 Bs[2][128][40];
  int tid = threadIdx.x;
  int wid = tid >> 6, lane = tid & 63;
  int lrow = lane & 15, quad = lane >> 4;
  // XCD swizzle: 1728 blocks, 216 per XCD; consecutive w share z (A-slice in L2)
  int lin = (blockIdx.z * 4 + blockIdx.y) * 9 + blockIdx.x;
  int w = (lin & 7) * 216 + (lin >> 3);
  int m0 = (w % 9) * 128;
  int rem = w / 9;                    // 0..191 = z*4 + y
  int n0 = (rem & 3) * 128;
  int z = rem >> 2;
  int t = z >> 4, b = z & 15;
  const unsigned* Ab = QF3 + (long long)z * 1052672;
  const __bf16* Bbh = Wth + (long long)t * 524288;
  const __bf16* Bbl = Wtl + (long long)t * 524288;

  int wm0 = (wid & 1) * 64, wn0 = (wid >> 1) * 64;
  // A staging: transpose packed [k][f] -> LDS [f][k], unpack hi/lo planes
  int floc = tid & 127;
  int kg = (tid >> 7) * 4;                 // 0 or 4
  const unsigned* Acol = Ab + min(m0 + floc, 1024);
  // B staging: plain copy of pre-split planes
  int srow = tid >> 1, shalf = tid & 1;

  f32x4 acc[4][4];
#pragma unroll
  for (int i = 0; i < 4; i++)
#pragma unroll
    for (int j = 0; j < 4; j++) acc[i][j] = (f32x4){0.f, 0.f, 0.f, 0.f};

  for (int k0 = 0; k0 < 1024; k0 += 32) {
#pragma unroll
    for (int it = 0; it < 4; it++) {
      int kko = kg + it * 8;               // 0,8,16,24 (+4)
      unsigned u0 = Acol[(long long)(k0 + kko + 0) * 1028];
      unsigned u1 = Acol[(long long)(k0 + kko + 1) * 1028];
      unsigned u2 = Acol[(long long)(k0 + kko + 2) * 1028];
      unsigned u3 = Acol[(long long)(k0 + kko + 3) * 1028];
      uint2 hu = make_uint2((u0 & 0xffffu) | (u1 << 16),
                            (u2 & 0xffffu) | (u3 << 16));
      uint2 lu = make_uint2((u0 >> 16) | (u1 & 0xffff0000u),
                            (u2 >> 16) | (u3 & 0xffff0000u));
      *(uint2*)&As[0][floc][kko] = hu;
      *(uint2*)&As[1][floc][kko] = lu;
    }
    {
      const __bf16* s = Bbh + (long long)(n0 + srow) * 1024 + k0 + shalf * 16;
      uint4* d = (uint4*)&Bs[0][srow][shalf * 16];
      d[0] = ((const uint4*)s)[0]; d[1] = ((const uint4*)s)[1];
      s = Bbl + (long long)(n0 + srow) * 1024 + k0 + shalf * 16;
      d = (uint4*)&Bs[1][srow][shalf * 16];
      d[0] = ((const uint4*)s)[0]; d[1] = ((const uint4*)s)[1];
    }
    __syncthreads();

    bf16x8 bh[4], bl[4];
#pragma unroll
    for (int nt = 0; nt < 4; nt++) {
      int r = wn0 + nt * 16 + lrow;
      bh[nt] = ldfrag(&Bs[0][r][quad * 8]);
      bl[nt] = ldfrag(&Bs[1][r][quad * 8]);
    }
#pragma unroll
    for (int mt = 0; mt < 4; mt++) {
      int r = wm0 + mt * 16 + lrow;
      bf16x8 ah = ldfrag(&As[0][r][quad * 8]);
      bf16x8 al = ldfrag(&As[1][r][quad * 8]);
#pragma unroll
      for (int nt = 0; nt < 4; nt++) {
        acc[mt][nt] = __builtin_amdgcn_mfma_f32_16x16x32_bf16(ah, bh[nt], acc[mt][nt], 0, 0, 0);
        acc[mt][nt] = __builtin_amdgcn_mfma_f32_16x16x32_bf16(ah, bl[nt], acc[mt][nt], 0, 0, 0);
        acc[mt][nt] = __builtin_amdgcn_mfma_f32_16x16x32_bf16(al, bh[nt], acc[mt][nt], 0, 0, 0);
      }
    }
    __syncthreads();
  }

  // epilogue
  __bf16* Ch = (t == 0) ? qhh : khh;
  __bf16* Cl = (t == 0) ? qhl : khl;
#pragma unroll
  for (int mt = 0; mt < 4; mt++) {
#pragma unroll
    for (int nt = 0; nt < 4; nt++) {
      int gn = n0 + wn0 + nt * 16 + lrow;
      float bn = bias3[t * 512 + gn];
      float vn = wf3[t * 512 + gn];
      int gmb = m0 + wm0 + mt * 16 + quad * 4;
      if (t < 2) {
#pragma unroll
        for (int r = 0; r < 4; r++) {
          int gm = gmb + r;
          if (gm < FL) {
            float val = acc[mt][nt][r] + bn + uscale * (float)gm * vn;
            long long o = ((long long)b * FL + gm) * 512 + gn;
            __bf16 h = (__bf16)val;
            Ch[o] = h;
            Cl[o] = (__bf16)(val - (float)h);
          }
        }
      } else {
        int hh = gn >> 6, dd = gn & 63;
        long long ob = ((long long)(b * 8 + hh) * 64 + dd) * 1152;
#pragma unroll
        for (int r = 0; r < 4; r++) {
          int gm = gmb + r;
          if (gm < FL) {
            float val = acc[mt][nt][r] + bn + uscale * (float)gm * vn;
            vhT[ob + gm] = (__bf16)val;
          }
        }
      }
    }
  }
}

// ---------------------------------------------------------------------------
// Out projection GEMM (1-term): A = ctx bf16 [b][f][512], B = Woh [o][512].
// Writes ybT[b][o=1024][f=1025] fp32 (transposed for coalesced irfft reads).
// XCD swizzle: 1152 blocks, 144 per XCD (FIXED round 2: was 162, non-bijective).
__global__ __launch_bounds__(256) void oproj_gemm(
    const __bf16* __restrict__ ctx, const __bf16* __restrict__ Woh,
    const float* __restrict__ bo, float* __restrict__ ybT) {
  __shared__ __bf16 As[128][40];
  __shared__ __bf16 Bs[128][40];
  int tid = threadIdx.x;
  int wid = tid >> 6, lane = tid & 63;
  int lrow = lane & 15, quad = lane >> 4;
  int lin = (blockIdx.z * 8 + blockIdx.y) * 9 + blockIdx.x;
  int w = (lin & 7) * 144 + (lin >> 3);
  int m0 = (w % 9) * 128;
  int rem = w / 9;                     // 0..127 = z*8 + y
  int n0 = (rem & 7) * 128;
  int z = rem >> 3;
  const __bf16* Ab = ctx + (long long)z * 524800;
  int wm0 = (wid & 1) * 64, wn0 = (wid >> 1) * 64;
  int srow = tid >> 1, shalf = tid & 1;
  int arow = min(m0 + srow, FL - 1);

  f32x4 acc[4][4];
#pragma unroll
  for (int i = 0; i < 4; i++)
#pragma unroll
    for (int j = 0; j < 4; j++) acc[i][j] = (f32x4){0.f, 0.f, 0.f, 0.f};

  for (int k0 = 0; k0 < 512; k0 += 32) {
    {
      const __bf16* s = Ab + (long long)arow * 512 + k0 + shalf * 16;
      uint4* d = (uint4*)&As[srow][shalf * 16];
      d[0] = ((const uint4*)s)[0]; d[1] = ((const uint4*)s)[1];
      s = Woh + (long long)(n0 + srow) * 512 + k0 + shalf * 16;
      d = (uint4*)&Bs[srow][shalf * 16];
      d[0] = ((const uint4*)s)[0]; d[1] = ((const uint4*)s)[1];
    }
    __syncthreads();
    bf16x8 bh[4];
#pragma unroll
    for (int nt = 0; nt < 4; nt++) bh[nt] = ldfrag(&Bs[wn0 + nt * 16 + lrow][quad * 8]);
#pragma unroll
    for (int mt = 0; mt < 4; mt++) {
      bf16x8 ah = ldfrag(&As[wm0 + mt * 16 + lrow][quad * 8]);
#pragma unroll
      for (int nt = 0; nt < 4; nt++)
        acc[mt][nt] = __builtin_amdgcn_mfma_f32_16x16x32_bf16(ah, bh[nt], acc[mt][nt], 0, 0, 0);
    }
    __syncthreads();
  }

#pragma unroll
  for (int mt = 0; mt < 4; mt++) {
#pragma unroll
    for (int nt = 0; nt < 4; nt++) {
      int gn = n0 + wn0 + nt * 16 + lrow;
      float bn = bo[gn];
      int gmb = m0 + wm0 + mt * 16 + quad * 4;
      long long ob = (long long)z * 1049600 + (long long)gn * 1025;
#pragma unroll
      for (int r = 0; r < 4; r++) {
        int gm = gmb + r;
        if (gm < FL) ybT[ob + gm] = acc[mt][nt][r] + bn;
      }
    }
  }
}

// ---------------------------------------------------------------------------
// Fused flash attention (verified round 3): per (b,h), 128-row Q tile,
// two-pass exact online softmax; writes normalized attn (fp32) + ctx (bf16).
static __device__ __forceinline__ void compute_S_tile(
    const __bf16 (*Kh)[72], const __bf16 (*Kl)[72],
    const bf16x8 (&qf)[2][2], int lrow, int quad, int n0, f32x4* sa) {
#pragma unroll
  for (int nt = 0; nt < 8; nt++) sa[nt] = (f32x4){0.f, 0.f, 0.f, 0.f};
#pragma unroll
  for (int kit = 0; kit < 2; kit++) {
#pragma unroll
    for (int nt = 0; nt < 8; nt++) {
      bf16x8 kh = ldfrag(&Kh[nt * 16 + lrow][kit * 32 + quad * 8]);
      bf16x8 kl = ldfrag(&Kl[nt * 16 + lrow][kit * 32 + quad * 8]);
      sa[nt] = __builtin_amdgcn_mfma_f32_16x16x32_bf16(qf[0][kit], kh, sa[nt], 0, 0, 0);
      sa[nt] = __builtin_amdgcn_mfma_f32_16x16x32_bf16(qf[0][kit], kl, sa[nt], 0, 0, 0);
      sa[nt] = __builtin_amdgcn_mfma_f32_16x16x32_bf16(qf[1][kit], kh, sa[nt], 0, 0, 0);
    }
  }
#pragma unroll
  for (int nt = 0; nt < 8; nt++) {
    int gn = n0 + nt * 16 + lrow;
    bool ok = gn < FL;
#pragma unroll
    for (int r = 0; r < 4; r++) sa[nt][r] = ok ? sa[nt][r] * 0.125f : -INFINITY;
  }
}

__global__ __launch_bounds__(512) void flash_kernel(
    const __bf16* __restrict__ qh_h, const __bf16* __restrict__ qh_l,
    const __bf16* __restrict__ kh_h, const __bf16* __restrict__ kh_l,
    const __bf16* __restrict__ vhT,
    float* __restrict__ attn, __bf16* __restrict__ ctxb) {
  __shared__ __align__(16) char smem[54272];
  __bf16 (*Kh)[72]  = (__bf16 (*)[72])smem;
  __bf16 (*Kl)[72]  = (__bf16 (*)[72])(smem + 18432);
  __bf16 (*P)[136]  = (__bf16 (*)[136])smem;          // aliases Kh/Kl
  __bf16 (*Bv)[136] = (__bf16 (*)[136])(smem + 36864);

  int tid = threadIdx.x;
  int wid = tid >> 6, lane = tid & 63;
  int lrow = lane & 15, quad = lane >> 4;
  // XCD swizzle: 1152 blocks, 144 per XCD; the 9 f0-tiles of one (b,h)
  // colocate so K/V stay in one XCD's L2.
  int lin = blockIdx.z * 9 + blockIdx.x;
  int w = (lin & 7) * 144 + (lin >> 3);
  int f0 = (w % 9) * 128;
  int z = w / 9;
  int b = z >> 3, h = z & 7;

  bf16x8 qf[2][2];
  {
    int rowq = min(f0 + wid * 16 + lrow, FL - 1);
    long long base = ((long long)b * FL + rowq) * 512 + h * 64 + quad * 8;
#pragma unroll
    for (int kit = 0; kit < 2; kit++) {
      qf[0][kit] = ldfrag(qh_h + base + kit * 32);
      qf[1][kit] = ldfrag(qh_l + base + kit * 32);
    }
  }

  int sp = tid >> 8, srw = (tid >> 1) & 127, shalf = tid & 1;
  const __bf16* ksrc0 = (sp ? kh_l : kh_h) + (long long)b * FL * 512 + h * 64 + shalf * 32;
  __bf16* kdst = (sp ? Kl[srw] : Kh[srw]) + shalf * 32;

  float m_i[4], l_i[4];
#pragma unroll
  for (int r = 0; r < 4; r++) { m_i[r] = -INFINITY; l_i[r] = 0.f; }

  f32x4 sa[8];

  // ---- pass 1: exact online (m, l) ----
  for (int nt0 = 0; nt0 < 9; nt0++) {
    __syncthreads();
    {
      int srowg = min(nt0 * 128 + srw, FL - 1);
      const __bf16* s = ksrc0 + (long long)srowg * 512;
#pragma unroll
      for (int u = 0; u < 4; u++) ((uint4*)kdst)[u] = ((const uint4*)s)[u];
    }
    __syncthreads();
    compute_S_tile(Kh, Kl, qf, lrow, quad, nt0 * 128, sa);
#pragma unroll
    for (int r = 0; r < 4; r++) {
      float mx = -INFINITY;
#pragma unroll
      for (int nt = 0; nt < 8; nt++) mx = fmaxf(mx, sa[nt][r]);
      for (int o = 1; o < 16; o <<= 1) mx = fmaxf(mx, __shfl_xor(mx, o, 64));
      float mn = fmaxf(m_i[r], mx);
      float al = fexp(m_i[r] - mn);
      float ps = 0.f;
#pragma unroll
      for (int nt = 0; nt < 8; nt++) ps += fexp(sa[nt][r] - mn);
      for (int o = 1; o < 16; o <<= 1) ps += __shfl_xor(ps, o, 64);
      l_i[r] = l_i[r] * al + ps;
      m_i[r] = mn;
    }
  }

  float rl[4];
#pragma unroll
  for (int r = 0; r < 4; r++) rl[r] = 1.0f / l_i[r];

  f32x4 oa[4];
#pragma unroll
  for (int j = 0; j < 4; j++) oa[j] = (f32x4){0.f, 0.f, 0.f, 0.f};

  int vrow = tid >> 3, voff = (tid & 7) * 16;
  const __bf16* vsrc0 = vhT + ((long long)z * 64 + vrow) * 1152 + voff;
  __bf16* vdst = &Bv[vrow][voff];

  // ---- pass 2: recompute S, emit attn, accumulate O = P*V ----
  float* attnz = attn + (long long)z * 1050625;
  for (int nt0 = 0; nt0 < 9; nt0++) {
    __syncthreads();
    {
      int srowg = min(nt0 * 128 + srw, FL - 1);
      const __bf16* s = ksrc0 + (long long)srowg * 512;
#pragma unroll
      for (int u = 0; u < 4; u++) ((uint4*)kdst)[u] = ((const uint4*)s)[u];
      const __bf16* vs = vsrc0 + nt0 * 128;
      ((uint4*)vdst)[0] = ((const uint4*)vs)[0];
      ((uint4*)vdst)[1] = ((const uint4*)vs)[1];
    }
    __syncthreads();
    compute_S_tile(Kh, Kl, qf, lrow, quad, nt0 * 128, sa);
    __syncthreads();
#pragma unroll
    for (int nt = 0; nt < 8; nt++) {
      int gn = nt0 * 128 + nt * 16 + lrow;
#pragma unroll
      for (int r = 0; r < 4; r++) {
        float p = fexp(sa[nt][r] - m_i[r]) * rl[r];
        int lm = wid * 16 + quad * 4 + r;
        int gm = f0 + lm;
        if (gm < FL && gn < FL) attnz[(long long)gm * FL + gn] = p;
        P[lm][nt * 16 + lrow] = (__bf16)p;
      }
    }
#pragma unroll
    for (int kk = 0; kk < 4; kk++) {
      bf16x8 pf = ldfrag(&P[wid * 16 + lrow][kk * 32 + quad * 8]);
#pragma unroll
      for (int nto = 0; nto < 4; nto++) {
        bf16x8 vf = ldfrag(&Bv[nto * 16 + lrow][kk * 32 + quad * 8]);
        oa[nto] = __builtin_amdgcn_mfma_f32_16x16x32_bf16(pf, vf, oa[nto], 0, 0, 0);
      }
    }
  }

#pragma unroll
  for (int nto = 0; nto < 4; nto++) {
#pragma unroll
    for (int r = 0; r < 4; r++) {
      int gm = f0 + wid * 16 + quad * 4 + r;
      if (gm < FL)
        ctxb[((long long)b * FL + gm) * 512 + h * 64 + nto * 16 + lrow] = (__bf16)oa[nto][r];
    }
  }
}

// ---------------------------------------------------------------------------
extern "C" void kernel_launch(void* const* d_in, const int* in_sizes, int n_in,
                              void* d_out, int out_size, void* d_ws, size_t ws_size,
                              hipStream_t stream) {
  (void)in_sizes; (void)n_in; (void)out_size; (void)ws_size;
  const float* q  = (const float*)d_in[0];
  const float* k  = (const float*)d_in[1];
  const float* v  = (const float*)d_in[2];
  const float* Wq = (const float*)d_in[3];
  const float* bq = (const float*)d_in[4];
  const float* Wk = (const float*)d_in[5];
  const float* bk = (const float*)d_in[6];
  const float* Wv = (const float*)d_in[7];
  const float* bv = (const float*)d_in[8];
  const float* Wo = (const float*)d_in[9];
  const float* bo = (const float*)d_in[10];

  float* outp = (float*)d_out;
  float* attn = outp + (long long)16 * 2048 * 512;

  float* ws = (float*)d_ws;
  float*  xT   = ws;                                   // 50,331,648 fl
  float*  QF3  = xT + 50331648;                        // 50,528,256 fl (48 x 1024 x 1028, packed hl)
  float*  wf3  = QF3 + 50528256;                       //      1,536 fl
  float*  bias3= wf3 + 1536;                           //      1,536 fl
  __bf16* Wth  = (__bf16*)(bias3 + 1536);              //  1,572,864
  __bf16* Wtl  = Wth + 1572864;
  __bf16* Woh  = Wtl + 1572864;                        //    524,288
  __bf16* qhh  = Woh + 524288;                         //  8,396,800 each
  __bf16* qhl  = qhh + 8396800;
  __bf16* khh  = qhl + 8396800;
  __bf16* khl  = khh + 8396800;
  __bf16* vhT  = khl + 8396800;                        //  9,437,184
  __bf16* ctx  = (__bf16*)QF3;                         // alias (QF3 dead post-proj)
  float*  ybT  = xT;                                   // alias (xT dead post-rfft)

  transpose_x<<<dim3(64, 16, 48), 256, 0, stream>>>(q, k, v, xT);
  setup_pack<<<dim3(8204, 1, 1), 256, 0, stream>>>(Wq, Wk, Wv, Wo, bq, bk, bv,
                                                   Wth, Wtl, Woh, wf3, bias3);
  rfft3_kernel<<<dim3(256, 16, 3), 256, 0, stream>>>(xT, (unsigned*)QF3);

  proj_gemm<<<dim3(9, 4, 48), 256, 0, stream>>>(
      (const unsigned*)QF3, Wth, Wtl, wf3, bias3, qhh, qhl, khh, khl, vhT,
      1.0f / 2048.0f);

  flash_kernel<<<dim3(9, 1, 128), 512, 0, stream>>>(
      qhh, qhl, khh, khl, vhT, attn, ctx);

  oproj_gemm<<<dim3(9, 8, 16), 256, 0, stream>>>(ctx, Woh, bo, ybT);

  irfft3_kernel<<<dim3(256, 16), 256, 0, stream>>>(ybT, outp);
}